// Round 7
// baseline (363.985 us; speedup 1.0000x reference)
//
#include <hip/hip_runtime.h>

// ---------------- problem constants ----------------
#define B_  128
#define N_  512
#define F_  128
#define L_  64
#define H_  128
#define C_  10

typedef short  bf8_t  __attribute__((ext_vector_type(8)));   // 8 x bf16 (MFMA A/B frag)
typedef float  f32x4  __attribute__((ext_vector_type(4)));   // MFMA C/D frag
typedef unsigned short us8 __attribute__((ext_vector_type(8)));

static __device__ __forceinline__ unsigned short f2bf(float x) {
    union { float f; unsigned u; } c; c.f = x;
    unsigned r = (c.u + 0x7fffu + ((c.u >> 16) & 1u)) >> 16;
    return (unsigned short)r;
}
static __device__ __forceinline__ float bf2f(unsigned short s) {
    union { unsigned u; float f; } c; c.u = ((unsigned)s) << 16;
    return c.f;
}
static __device__ __forceinline__ float elu(float x) { return x > 0.f ? x : expm1f(x); }

// ws layout (float units) — no zero-init required (ticket zeroed by k1 each iteration)
#define OFF_DEGP   0           // 2097152  deg partials [b][32][512]
#define OFF_DEG    2097152     // 65536
#define OFF_HPP    2162688     // 65536    hp partials [8][b][64]
#define OFF_KLP    2228224     // 1024     [b*8+c]
#define OFF_MSEP   2229248     // 1024     [b*8+c]
#define OFF_V      2230272     // 65536    v (f32)
#define OFF_LP     2295808     // 128
#define OFF_COR    2295936     // 128
#define OFF_KLB    2296064     // 128      per-batch kl sums
#define OFF_MSEB   2296192     // 128      per-batch mse sums
#define OFF_TMUBF  2296320     // 32768    tmu bf16 [b][512]  (as 16384 floats; keep 32768 slack)
#define OFF_TLVBF  2329088     // tlv bf16 [b][512]
#define OFF_WVBF   2361856     // w   bf16 [b][512]
#define OFF_H1Q    2394624     // 2097152  h1 bf16 [b][n][l]
#define OFF_GBF    4491776     // 16777216 g bf16 [b][n][m]
#define OFF_UBFT   21269000    // (aligned below) u^T bf16 [b][l][m]
#define OFF_UBFT2  21269504    // use this (16-aligned)
#define OFF_HWT    23366656    // 4194304  hW^T f32 [b][l][m]
#define OFF_TICKET 27560960    // 1 uint

// ---------------- k1: grid (9,B). x<8: g -> bf16 + column-sum partials. x==8: hW^T MFMA ----------------
__global__ __launch_bounds__(256) void k1_deg(const float* __restrict__ g,
                                              const float* __restrict__ h,
                                              const float* __restrict__ Ws,
                                              float* __restrict__ deg_part,
                                              unsigned short* __restrict__ gbf,
                                              float* __restrict__ hwT,
                                              unsigned* __restrict__ ticket) {
    __shared__ unsigned short wst[64 * 128];
    const int b = blockIdx.y;
    const int tid = threadIdx.x;
    const int w = tid >> 6, lane = tid & 63;

    if (blockIdx.x == 8) {
        // side lane: hW^T[l][m] = sum_f Ws^T[l][f] * h[m][f]  (undivided, f32 out)
        if (b == 0 && tid == 0) *ticket = 0u;
        for (int i = tid; i < F_ * L_; i += 256) {
            int l = i >> 7, f = i & 127;
            wst[l * F_ + (f ^ ((l & 7) << 3))] = f2bf(Ws[f * L_ + l]);
        }
        __syncthreads();
        const int ml = lane & 15, q = lane >> 4;
        for (int sub = 0; sub < 8; ++sub) {
            const int m0 = (sub * 4 + w) * 16;
            const float* Bp = h + (size_t)(b * N_ + m0 + ml) * F_ + q * 8;
            f32x4 acc[4] = {};
            #pragma unroll
            for (int kk = 0; kk < F_; kk += 32) {
                float4 b0 = *reinterpret_cast<const float4*>(Bp + kk);
                float4 b1 = *reinterpret_cast<const float4*>(Bp + kk + 4);
                union { unsigned short s[8]; bf8_t v; } bv;
                bv.s[0] = f2bf(b0.x); bv.s[1] = f2bf(b0.y); bv.s[2] = f2bf(b0.z); bv.s[3] = f2bf(b0.w);
                bv.s[4] = f2bf(b1.x); bv.s[5] = f2bf(b1.y); bv.s[6] = f2bf(b1.z); bv.s[7] = f2bf(b1.w);
                #pragma unroll
                for (int i = 0; i < 4; ++i) {
                    const int l = i * 16 + ml;
                    bf8_t av = *reinterpret_cast<const bf8_t*>(
                        wst + l * F_ + ((q * 8 + kk) ^ ((ml & 7) << 3)));
                    acc[i] = __builtin_amdgcn_mfma_f32_16x16x32_bf16(av, bv.v, acc[i], 0, 0, 0);
                }
            }
            #pragma unroll
            for (int i = 0; i < 4; ++i) {
                #pragma unroll
                for (int r = 0; r < 4; ++r) {
                    int l = i * 16 + 4 * q + r;
                    hwT[(size_t)(b * L_ + l) * N_ + m0 + ml] = acc[i][r];
                }
            }
        }
        return;
    }

    const int c8 = blockIdx.x;
    const int r0 = c8 * 64 + w * 16;
    const float*    gp = g   + ((size_t)b * N_ + r0) * N_ + lane * 8;
    unsigned short* gq = gbf + ((size_t)b * N_ + r0) * N_ + lane * 8;
    float cs[8] = {};
    #pragma unroll 4
    for (int r = 0; r < 16; ++r) {
        float4 v0 = *reinterpret_cast<const float4*>(gp + (size_t)r * N_);
        float4 v1 = *reinterpret_cast<const float4*>(gp + (size_t)r * N_ + 4);
        cs[0] += v0.x; cs[1] += v0.y; cs[2] += v0.z; cs[3] += v0.w;
        cs[4] += v1.x; cs[5] += v1.y; cs[6] += v1.z; cs[7] += v1.w;
        us8 qv;
        qv[0] = f2bf(v0.x); qv[1] = f2bf(v0.y); qv[2] = f2bf(v0.z); qv[3] = f2bf(v0.w);
        qv[4] = f2bf(v1.x); qv[5] = f2bf(v1.y); qv[6] = f2bf(v1.z); qv[7] = f2bf(v1.w);
        *reinterpret_cast<us8*>(gq + (size_t)r * N_) = qv;
    }
    const int s = c8 * 4 + w;   // slice 0..31
    float* dp = deg_part + ((size_t)(b * 32 + s)) * N_ + lane * 8;
    *reinterpret_cast<float4*>(dp)     = make_float4(cs[0], cs[1], cs[2], cs[3]);
    *reinterpret_cast<float4*>(dp + 4) = make_float4(cs[4], cs[5], cs[6], cs[7]);
}

// ---------------- k2p: finalize deg; ubfT = bf16(hwT / deg) ----------------
// grid (8, B_), 256 thr; block handles 64 m-cols.
__global__ __launch_bounds__(256) void k2p(const float* __restrict__ deg_part,
                                           const float* __restrict__ hwT,
                                           float* __restrict__ deg,
                                           unsigned short* __restrict__ ubfT) {
    __shared__ float sdeg[64];
    const int b = blockIdx.y, mc = blockIdx.x, tid = threadIdx.x;
    if (tid < 64) {
        int col = mc * 64 + tid;
        float s = 0.f;
        #pragma unroll
        for (int k = 0; k < 32; ++k) s += deg_part[(size_t)(b * 32 + k) * N_ + col];
        sdeg[tid] = s;
        deg[b * N_ + col] = s;
    }
    __syncthreads();
    const int m = mc * 64 + (tid & 63);
    const float idg = 1.f / sdeg[tid & 63];
    #pragma unroll
    for (int l = tid >> 6; l < 64; l += 4)
        ubfT[(size_t)(b * L_ + l) * N_ + m] = f2bf(hwT[(size_t)(b * L_ + l) * N_ + m] * idg);
}

// ---------------- k3: h1 = ELU(g@u + b_s) via MFMA; fused tmu/tlv (bf16) ----------------
__global__ __launch_bounds__(256) void k3_h1(const unsigned short* __restrict__ gbf,
                                             const unsigned short* __restrict__ ubfT,
                                             const float* __restrict__ b_s,
                                             const float* __restrict__ Wmu,
                                             const float* __restrict__ Wlv,
                                             const float* __restrict__ deg,
                                             unsigned short* __restrict__ h1q,
                                             unsigned short* __restrict__ tmubf,
                                             unsigned short* __restrict__ tlvbf) {
    const int b    = blockIdx.y;
    const int tid  = threadIdx.x;
    const int wave = tid >> 6, lane = tid & 63;
    const int row0 = blockIdx.x * 64 + wave * 16;
    const int ml = lane & 15, q = lane >> 4;

    const unsigned short* A  = gbf  + (size_t)(b * N_ + row0 + ml) * N_ + q * 8;
    const unsigned short* B0 = ubfT + (size_t)(b * L_ + ml) * N_ + q * 8;

    f32x4 acc[4] = {};
    #pragma unroll 4
    for (int k = 0; k < N_; k += 32) {
        bf8_t a = *reinterpret_cast<const bf8_t*>(A + k);
        #pragma unroll
        for (int i = 0; i < 4; ++i) {
            bf8_t bb = *reinterpret_cast<const bf8_t*>(B0 + (size_t)i * 16 * N_ + k);
            acc[i] = __builtin_amdgcn_mfma_f32_16x16x32_bf16(a, bb, acc[i], 0, 0, 0);
        }
    }
    float bsv[4], wm[4], wl[4];
    #pragma unroll
    for (int i = 0; i < 4; ++i) {
        int col = i * 16 + ml;
        bsv[i] = b_s[col]; wm[i] = Wmu[col]; wl[i] = Wlv[col];
    }
    #pragma unroll
    for (int r = 0; r < 4; ++r) {
        int row = row0 + 4 * q + r;
        float pm = 0.f, pl = 0.f;
        #pragma unroll
        for (int i = 0; i < 4; ++i) {
            float hv = elu(acc[i][r] + bsv[i]);
            h1q[(size_t)(b * N_ + row) * L_ + i * 16 + ml] = f2bf(hv);
            pm = fmaf(hv, wm[i], pm);
            pl = fmaf(hv, wl[i], pl);
        }
        #pragma unroll
        for (int o = 1; o < 16; o <<= 1) { pm += __shfl_xor(pm, o); pl += __shfl_xor(pl, o); }
        if (ml == 0) {
            float idg = 1.f / deg[b * N_ + row];
            tmubf[b * N_ + row] = f2bf(pm * idg);
            tlvbf[b * N_ + row] = f2bf(pl * idg);
        }
    }
}

// ---------------- k5: amu/alv via MFMA (B cols 0/1 = tmu/tlv); z -> v, w; KL partial ----------------
__global__ __launch_bounds__(256) void k5_v(const unsigned short* __restrict__ gbf,
                                            const unsigned short* __restrict__ tmubf,
                                            const unsigned short* __restrict__ tlvbf,
                                            const float* __restrict__ eps, const float* __restrict__ deg,
                                            const float* __restrict__ bmu, const float* __restrict__ blv,
                                            const float* __restrict__ beta,
                                            float* __restrict__ vv, unsigned short* __restrict__ wvbf,
                                            float* __restrict__ kl_part) {
    __shared__ float kls[4];
    const int b = blockIdx.y;
    const int wave = threadIdx.x >> 6, lane = threadIdx.x & 63;
    const int ml = lane & 15, q = lane >> 4;
    const int n0 = (blockIdx.x * 4 + wave) * 16;

    const unsigned short* A  = gbf + (size_t)(b * N_ + n0 + ml) * N_ + q * 8;
    const unsigned short* Bp = ((ml & 1) ? tlvbf : tmubf) + (size_t)b * N_ + q * 8;

    f32x4 acc = {};
    #pragma unroll
    for (int k = 0; k < N_; k += 32) {
        bf8_t a  = *reinterpret_cast<const bf8_t*>(A + k);
        bf8_t bb = *reinterpret_cast<const bf8_t*>(Bp + k);
        acc = __builtin_amdgcn_mfma_f32_16x16x32_bf16(a, bb, acc, 0, 0, 0);
    }
    float alv4[4];
    #pragma unroll
    for (int r = 0; r < 4; ++r) alv4[r] = __shfl_xor(acc[r], 1);

    float klv = 0.f;
    if (ml == 0) {
        const float bmu0 = bmu[0], blv0 = blv[0], beta0 = beta[0];
        #pragma unroll
        for (int r = 0; r < 4; ++r) {
            int n = n0 + 4 * q + r;
            float mu = elu(acc[r] + bmu0);
            float lv = elu(alv4[r] + blv0);
            float z  = mu + eps[b * N_ + n] * expf(0.5f * lv);
            float vs = 1.f / (1.f + expf(-beta0 * z));
            vv[b * N_ + n]   = vs;
            wvbf[b * N_ + n] = f2bf(vs / deg[b * N_ + n]);
            float e = expf(lv);
            klv += 1.f + 2.f * lv - mu * mu - e * e;
        }
    }
    klv += __shfl_xor(klv, 16);
    klv += __shfl_xor(klv, 32);
    if (lane == 0) kls[wave] = klv;
    __syncthreads();
    if (threadIdx.x == 0)
        kl_part[b * 8 + blockIdx.x] = kls[0] + kls[1] + kls[2] + kls[3];
}

// ---------------- k6: p = g@w via MFMA; d = ELU(p*W_dec+b_dec); mse + hp partials ----------------
__global__ __launch_bounds__(256) void k6_dec(const unsigned short* __restrict__ gbf,
                                              const unsigned short* __restrict__ wvbf,
                                              const float* __restrict__ vv,
                                              const unsigned short* __restrict__ h1q,
                                              const float* __restrict__ Wdec, const float* __restrict__ bdec,
                                              float* __restrict__ hp_part, float* __restrict__ mse_part) {
    __shared__ float hps[4 * 64];
    __shared__ float mses[4];
    const int b = blockIdx.y;
    const int tid = threadIdx.x, wave = tid >> 6, lane = tid & 63;
    const int ml = lane & 15, q = lane >> 4;
    const int n0 = (blockIdx.x * 4 + wave) * 16;

    const unsigned short* A  = gbf  + (size_t)(b * N_ + n0 + ml) * N_ + q * 8;
    const unsigned short* Bp = wvbf + (size_t)b * N_ + q * 8;

    f32x4 acc = {};
    #pragma unroll
    for (int k = 0; k < N_; k += 32) {
        bf8_t a  = *reinterpret_cast<const bf8_t*>(A + k);
        bf8_t bb = *reinterpret_cast<const bf8_t*>(Bp + k);
        acc = __builtin_amdgcn_mfma_f32_16x16x32_bf16(a, bb, acc, 0, 0, 0);
    }
    float pbc[16];
    #pragma unroll
    for (int t = 0; t < 16; ++t) pbc[t] = __shfl(acc[t & 3], (t >> 2) << 4);

    const float wd = Wdec[lane], bd = bdec[lane];
    float hpl = 0.f, msep = 0.f;
    #pragma unroll 4
    for (int t = 0; t < 16; ++t) {
        int n = n0 + t;
        float dv  = elu(pbc[t] * wd + bd);
        float h1v = bf2f(h1q[(size_t)(b * N_ + n) * L_ + lane]);
        float diff = h1v - dv;
        msep = fmaf(diff, diff, msep);
        hpl  = fmaf(h1v, vv[b * N_ + n], hpl);
    }
    hps[wave * 64 + lane] = hpl;
    #pragma unroll
    for (int o = 32; o; o >>= 1) msep += __shfl_xor(msep, o);
    if (lane == 0) mses[wave] = msep;
    __syncthreads();
    if (tid < 64) {
        float s = hps[tid] + hps[64 + tid] + hps[128 + tid] + hps[192 + tid];
        hp_part[(size_t)blockIdx.x * (B_ * 64) + b * 64 + tid] = s;
    }
    if (tid == 0)
        mse_part[b * 8 + blockIdx.x] = mses[0] + mses[1] + mses[2] + mses[3];
}

// ---------------- k7: per-batch head + ticketed final reduce (last block) ----------------
__global__ __launch_bounds__(128) void k7_head(const float* __restrict__ hp_part,
                                               const float* __restrict__ W1, const float* __restrict__ b1,
                                               const float* __restrict__ W2, const float* __restrict__ b2,
                                               const int* __restrict__ labels,
                                               const float* __restrict__ kl_part, const float* __restrict__ mse_part,
                                               float* __restrict__ lp, float* __restrict__ cor,
                                               float* __restrict__ klb, float* __restrict__ mseb,
                                               unsigned* __restrict__ ticket, float* __restrict__ out) {
    __shared__ float hps[64];
    __shared__ float acts[128];
    __shared__ float lgs[10];
    __shared__ unsigned sold;
    const int b = blockIdx.x, tid = threadIdx.x;
    if (tid < 64) {
        float s = 0.f;
        #pragma unroll
        for (int x = 0; x < 8; ++x) s += hp_part[(size_t)x * (B_ * 64) + b * 64 + tid];
        hps[tid] = s;
    }
    __syncthreads();
    float s0 = 0, s1 = 0, s2 = 0, s3 = 0;
    for (int l = 0; l < 64; l += 4) {
        s0 += hps[l]     * W1[(l)     * H_ + tid];
        s1 += hps[l + 1] * W1[(l + 1) * H_ + tid];
        s2 += hps[l + 2] * W1[(l + 2) * H_ + tid];
        s3 += hps[l + 3] * W1[(l + 3) * H_ + tid];
    }
    acts[tid] = elu((s0 + s1) + (s2 + s3) + b1[tid]);
    __syncthreads();
    if (tid < C_) {
        float lg = b2[tid];
        for (int hh = 0; hh < H_; ++hh) lg += acts[hh] * W2[hh * C_ + tid];
        lgs[tid] = lg;
    }
    __syncthreads();
    if (tid == 0) {
        float mx = lgs[0]; int am = 0;
        for (int c = 1; c < C_; ++c) if (lgs[c] > mx) { mx = lgs[c]; am = c; }
        float se = 0.f;
        for (int c = 0; c < C_; ++c) se += expf(lgs[c] - mx);
        int lbl = labels[b];
        lp[b]  = lgs[lbl] - mx - logf(se);
        cor[b] = (am == lbl) ? 1.f : 0.f;
    }
    if (tid == 1) {
        float kk = 0.f;
        #pragma unroll
        for (int c = 0; c < 8; ++c) kk += kl_part[b * 8 + c];
        klb[b] = kk;
    }
    if (tid == 2) {
        float mm = 0.f;
        #pragma unroll
        for (int c = 0; c < 8; ++c) mm += mse_part[b * 8 + c];
        mseb[b] = mm;
    }
    if (tid < 3) __threadfence();   // release this block's results device-wide
    __syncthreads();
    if (tid == 0) sold = atomicAdd(ticket, 1u);
    __syncthreads();
    if (sold == 127u) {             // last block: all 128 results visible
        __threadfence();            // acquire
        __shared__ float r1[128], r2[128], r3[128], r4[128];
        r1[tid] = lp[tid]; r2[tid] = cor[tid]; r3[tid] = klb[tid]; r4[tid] = mseb[tid];
        __syncthreads();
        for (int o = 64; o; o >>= 1) {
            if (tid < o) { r1[tid] += r1[tid + o]; r2[tid] += r2[tid + o];
                           r3[tid] += r3[tid + o]; r4[tid] += r4[tid + o]; }
            __syncthreads();
        }
        if (tid == 0) {
            float nll = -r1[0] / (float)B_;
            float kl  = r3[0] * (-0.5f / (65536.f * 65536.f));   // (-0.5/M)*(sum/M), M = B*N
            float mse = r4[0] / (float)(B_ * N_ * L_);
            out[0] = nll + kl + mse;
            out[1] = r2[0] / (float)B_;
        }
    }
}

extern "C" void kernel_launch(void* const* d_in, const int* in_sizes, int n_in,
                              void* d_out, int out_size, void* d_ws, size_t ws_size,
                              hipStream_t stream) {
    const float* g     = (const float*)d_in[0];
    const float* h     = (const float*)d_in[1];
    const int*   labels= (const int*)  d_in[2];
    const float* eps   = (const float*)d_in[3];
    const float* W_s   = (const float*)d_in[4];
    const float* b_s   = (const float*)d_in[5];
    const float* W_mu  = (const float*)d_in[6];
    const float* b_mu  = (const float*)d_in[7];
    const float* W_lv  = (const float*)d_in[8];
    const float* b_lv  = (const float*)d_in[9];
    const float* W_dec = (const float*)d_in[10];
    const float* b_dec = (const float*)d_in[11];
    const float* W1    = (const float*)d_in[12];
    const float* b1    = (const float*)d_in[13];
    const float* W2    = (const float*)d_in[14];
    const float* b2    = (const float*)d_in[15];
    const float* beta  = (const float*)d_in[16];

    float* ws = (float*)d_ws;
    float* deg_part = ws + OFF_DEGP;
    float* deg      = ws + OFF_DEG;
    float* hp_part  = ws + OFF_HPP;
    float* kl_part  = ws + OFF_KLP;
    float* mse_part = ws + OFF_MSEP;
    float* vv       = ws + OFF_V;
    float* lp       = ws + OFF_LP;
    float* cor      = ws + OFF_COR;
    float* klb      = ws + OFF_KLB;
    float* mseb     = ws + OFF_MSEB;
    float* hwT      = ws + OFF_HWT;
    unsigned* ticket = (unsigned*)(ws + OFF_TICKET);
    unsigned short* tmubf = (unsigned short*)(ws + OFF_TMUBF);
    unsigned short* tlvbf = (unsigned short*)(ws + OFF_TLVBF);
    unsigned short* wvbf  = (unsigned short*)(ws + OFF_WVBF);
    unsigned short* h1q   = (unsigned short*)(ws + OFF_H1Q);
    unsigned short* gbf   = (unsigned short*)(ws + OFF_GBF);
    unsigned short* ubfT  = (unsigned short*)(ws + OFF_UBFT2);

    k1_deg <<<dim3(9, B_), 256, 0, stream>>>(g, h, W_s, deg_part, gbf, hwT, ticket);
    k2p    <<<dim3(8, B_), 256, 0, stream>>>(deg_part, hwT, deg, ubfT);
    k3_h1  <<<dim3(8, B_), 256, 0, stream>>>(gbf, ubfT, b_s, W_mu, W_lv, deg, h1q, tmubf, tlvbf);
    k5_v   <<<dim3(8, B_), 256, 0, stream>>>(gbf, tmubf, tlvbf, eps, deg, b_mu, b_lv, beta, vv, wvbf, kl_part);
    k6_dec <<<dim3(8, B_), 256, 0, stream>>>(gbf, wvbf, vv, h1q, W_dec, b_dec, hp_part, mse_part);
    k7_head<<<B_, 128, 0, stream>>>(hp_part, W1, b1, W2, b2, labels, kl_part, mse_part,
                                    lp, cor, klb, mseb, ticket, (float*)d_out);
}

// Round 8
// 355.694 us; speedup vs baseline: 1.0233x; 1.0233x over previous
//
#include <hip/hip_runtime.h>

// ---------------- problem constants ----------------
#define B_  128
#define N_  512
#define F_  128
#define L_  64
#define H_  128
#define C_  10

typedef short  bf8_t  __attribute__((ext_vector_type(8)));   // 8 x bf16 (MFMA A/B frag)
typedef float  f32x4  __attribute__((ext_vector_type(4)));   // MFMA C/D frag
typedef unsigned short us8 __attribute__((ext_vector_type(8)));

static __device__ __forceinline__ unsigned short f2bf(float x) {
    union { float f; unsigned u; } c; c.f = x;
    unsigned r = (c.u + 0x7fffu + ((c.u >> 16) & 1u)) >> 16;
    return (unsigned short)r;
}
static __device__ __forceinline__ float bf2f(unsigned short s) {
    union { unsigned u; float f; } c; c.u = ((unsigned)s) << 16;
    return c.f;
}
static __device__ __forceinline__ float elu(float x) { return x > 0.f ? x : expm1f(x); }

// ws layout (float units) — ticket zeroed by k1 each launch; nothing else needs init
#define OFF_DEGP   0           // 4194304  deg partials [b][64][512]
#define OFF_DEG    4194304     // 65536
#define OFF_HPP    4259840     // 65536    hp partials [8][b][64]
#define OFF_KLP    4325376     // 1024     [b*8+c]
#define OFF_MSEP   4326400     // 1024     [b*8+c]
#define OFF_V      4327424     // 65536    v (f32)
#define OFF_LP     4392960     // 128
#define OFF_COR    4393088     // 128
#define OFF_KLB    4393216     // 128      per-batch kl sums
#define OFF_MSEB   4393344     // 128      per-batch mse sums
#define OFF_TMUBF  4393472     // 16384 fl tmu bf16 [b][512]
#define OFF_TLVBF  4409856     // 16384 fl tlv bf16
#define OFF_WVBF   4426240     // 16384 fl w bf16
#define OFF_H1Q    4442624     // 2097152  h1 bf16 [b][n][l]
#define OFF_GBF    6539776     // 16777216 g bf16 [b][n][m]
#define OFF_UBFT   23316992    // 2097152  u^T bf16 [b][l][m]
#define OFF_WSTBF  25414144    // 4096     W_s^T bf16
#define OFF_TICKET 25418240    // 1 uint

// ---------------- k1: g -> bf16 (us8) + column-sum partials; grid (16,B) for full occupancy ----------------
// Block c covers rows [c*32, +32); wave w owns 8 rows; lane owns 8 cols.
__global__ __launch_bounds__(256) void k1_deg(const float* __restrict__ g,
                                              const float* __restrict__ Ws,
                                              float* __restrict__ deg_part,
                                              unsigned short* __restrict__ gbf,
                                              unsigned short* __restrict__ WsTbf,
                                              unsigned* __restrict__ ticket) {
    const int c = blockIdx.x, b = blockIdx.y;
    if (c == 0 && b == 0) {
        if (threadIdx.x == 0) *ticket = 0u;
        for (int i = threadIdx.x; i < F_ * L_; i += 256) {
            int l = i >> 7, f = i & 127;                 // dest [l][f]
            WsTbf[i] = f2bf(Ws[f * L_ + l]);
        }
    }
    const int w = threadIdx.x >> 6, lane = threadIdx.x & 63;
    const int r0 = c * 32 + w * 8;
    const float*    gp = g   + ((size_t)b * N_ + r0) * N_ + lane * 8;
    unsigned short* gq = gbf + ((size_t)b * N_ + r0) * N_ + lane * 8;
    float cs[8] = {};
    #pragma unroll
    for (int r = 0; r < 8; ++r) {
        float4 v0 = *reinterpret_cast<const float4*>(gp + (size_t)r * N_);
        float4 v1 = *reinterpret_cast<const float4*>(gp + (size_t)r * N_ + 4);
        cs[0] += v0.x; cs[1] += v0.y; cs[2] += v0.z; cs[3] += v0.w;
        cs[4] += v1.x; cs[5] += v1.y; cs[6] += v1.z; cs[7] += v1.w;
        us8 qv;
        qv[0] = f2bf(v0.x); qv[1] = f2bf(v0.y); qv[2] = f2bf(v0.z); qv[3] = f2bf(v0.w);
        qv[4] = f2bf(v1.x); qv[5] = f2bf(v1.y); qv[6] = f2bf(v1.z); qv[7] = f2bf(v1.w);
        *reinterpret_cast<us8*>(gq + (size_t)r * N_) = qv;
    }
    const int s = c * 4 + w;   // slice 0..63
    float* dp = deg_part + ((size_t)(b * 64 + s)) * N_ + lane * 8;
    *reinterpret_cast<float4*>(dp)     = make_float4(cs[0], cs[1], cs[2], cs[3]);
    *reinterpret_cast<float4*>(dp + 4) = make_float4(cs[4], cs[5], cs[6], cs[7]);
}

// ---------------- k2: finalize deg (64 slices); u^T (bf16) = ((h @ W_s)/deg)^T via MFMA ----------------
__global__ __launch_bounds__(256) void k2_u(const float* __restrict__ h,
                                            const unsigned short* __restrict__ WsTbf,
                                            const float* __restrict__ deg_part,
                                            float* __restrict__ deg,
                                            unsigned short* __restrict__ ubfT) {
    __shared__ float tile[64 * 65];
    __shared__ float sdeg[64];
    const int b    = blockIdx.y;
    const int m0   = blockIdx.x * 64;
    const int tid  = threadIdx.x;
    const int wave = tid >> 6, lane = tid & 63;
    const int ml = lane & 15, q = lane >> 4;
    const int row0 = wave * 16;

    if (tid < 64) {
        int j = m0 + tid;
        float s = 0.f;
        #pragma unroll
        for (int k = 0; k < 64; ++k) s += deg_part[(size_t)(b * 64 + k) * N_ + j];
        sdeg[tid] = s;
        deg[b * N_ + j] = s;
    }

    const float* A = h + (size_t)(b * N_ + m0 + row0 + ml) * F_ + q * 8;
    const unsigned short* Bb = WsTbf + ml * F_ + q * 8;

    f32x4 acc[4] = {};
    #pragma unroll
    for (int kk = 0; kk < F_; kk += 32) {
        float4 a0 = *reinterpret_cast<const float4*>(A + kk);
        float4 a1 = *reinterpret_cast<const float4*>(A + kk + 4);
        union { unsigned short s[8]; bf8_t v; } av;
        av.s[0] = f2bf(a0.x); av.s[1] = f2bf(a0.y); av.s[2] = f2bf(a0.z); av.s[3] = f2bf(a0.w);
        av.s[4] = f2bf(a1.x); av.s[5] = f2bf(a1.y); av.s[6] = f2bf(a1.z); av.s[7] = f2bf(a1.w);
        #pragma unroll
        for (int i = 0; i < 4; ++i) {
            bf8_t bv = *reinterpret_cast<const bf8_t*>(Bb + i * 16 * F_ + kk);
            acc[i] = __builtin_amdgcn_mfma_f32_16x16x32_bf16(av.v, bv, acc[i], 0, 0, 0);
        }
    }
    __syncthreads();   // sdeg ready; tile not yet written
    #pragma unroll
    for (int i = 0; i < 4; ++i) {
        int col = i * 16 + ml;
        #pragma unroll
        for (int r = 0; r < 4; ++r) {
            int rl = row0 + 4 * q + r;
            tile[rl * 65 + col] = acc[i][r] / sdeg[rl];
        }
    }
    __syncthreads();
    for (int jj = 0; jj < 16; ++jj) {
        int ll = wave + jj * 4;
        ubfT[(size_t)(b * L_ + ll) * N_ + m0 + lane] = f2bf(tile[lane * 65 + ll]);
    }
}

// ---------------- k3: h1 = ELU(g@u + b_s) via MFMA; fused tmu/tlv (bf16) ----------------
__global__ __launch_bounds__(256) void k3_h1(const unsigned short* __restrict__ gbf,
                                             const unsigned short* __restrict__ ubfT,
                                             const float* __restrict__ b_s,
                                             const float* __restrict__ Wmu,
                                             const float* __restrict__ Wlv,
                                             const float* __restrict__ deg,
                                             unsigned short* __restrict__ h1q,
                                             unsigned short* __restrict__ tmubf,
                                             unsigned short* __restrict__ tlvbf) {
    const int b    = blockIdx.y;
    const int tid  = threadIdx.x;
    const int wave = tid >> 6, lane = tid & 63;
    const int row0 = blockIdx.x * 64 + wave * 16;
    const int ml = lane & 15, q = lane >> 4;

    const unsigned short* A  = gbf  + (size_t)(b * N_ + row0 + ml) * N_ + q * 8;
    const unsigned short* B0 = ubfT + (size_t)(b * L_ + ml) * N_ + q * 8;

    f32x4 acc[4] = {};
    #pragma unroll 4
    for (int k = 0; k < N_; k += 32) {
        bf8_t a = *reinterpret_cast<const bf8_t*>(A + k);
        #pragma unroll
        for (int i = 0; i < 4; ++i) {
            bf8_t bb = *reinterpret_cast<const bf8_t*>(B0 + (size_t)i * 16 * N_ + k);
            acc[i] = __builtin_amdgcn_mfma_f32_16x16x32_bf16(a, bb, acc[i], 0, 0, 0);
        }
    }
    float bsv[4], wm[4], wl[4];
    #pragma unroll
    for (int i = 0; i < 4; ++i) {
        int col = i * 16 + ml;
        bsv[i] = b_s[col]; wm[i] = Wmu[col]; wl[i] = Wlv[col];
    }
    #pragma unroll
    for (int r = 0; r < 4; ++r) {
        int row = row0 + 4 * q + r;
        float pm = 0.f, pl = 0.f;
        #pragma unroll
        for (int i = 0; i < 4; ++i) {
            float hv = elu(acc[i][r] + bsv[i]);
            h1q[(size_t)(b * N_ + row) * L_ + i * 16 + ml] = f2bf(hv);
            pm = fmaf(hv, wm[i], pm);
            pl = fmaf(hv, wl[i], pl);
        }
        #pragma unroll
        for (int o = 1; o < 16; o <<= 1) { pm += __shfl_xor(pm, o); pl += __shfl_xor(pl, o); }
        if (ml == 0) {
            float idg = 1.f / deg[b * N_ + row];
            tmubf[b * N_ + row] = f2bf(pm * idg);
            tlvbf[b * N_ + row] = f2bf(pl * idg);
        }
    }
}

// ---------------- k5: amu/alv via MFMA (B cols 0/1 = tmu/tlv); z -> v, w; KL partial ----------------
__global__ __launch_bounds__(256) void k5_v(const unsigned short* __restrict__ gbf,
                                            const unsigned short* __restrict__ tmubf,
                                            const unsigned short* __restrict__ tlvbf,
                                            const float* __restrict__ eps, const float* __restrict__ deg,
                                            const float* __restrict__ bmu, const float* __restrict__ blv,
                                            const float* __restrict__ beta,
                                            float* __restrict__ vv, unsigned short* __restrict__ wvbf,
                                            float* __restrict__ kl_part) {
    __shared__ float kls[4];
    const int b = blockIdx.y;
    const int wave = threadIdx.x >> 6, lane = threadIdx.x & 63;
    const int ml = lane & 15, q = lane >> 4;
    const int n0 = (blockIdx.x * 4 + wave) * 16;

    const unsigned short* A  = gbf + (size_t)(b * N_ + n0 + ml) * N_ + q * 8;
    const unsigned short* Bp = ((ml & 1) ? tlvbf : tmubf) + (size_t)b * N_ + q * 8;

    f32x4 acc = {};
    #pragma unroll
    for (int k = 0; k < N_; k += 32) {
        bf8_t a  = *reinterpret_cast<const bf8_t*>(A + k);
        bf8_t bb = *reinterpret_cast<const bf8_t*>(Bp + k);
        acc = __builtin_amdgcn_mfma_f32_16x16x32_bf16(a, bb, acc, 0, 0, 0);
    }
    float alv4[4];
    #pragma unroll
    for (int r = 0; r < 4; ++r) alv4[r] = __shfl_xor(acc[r], 1);

    float klv = 0.f;
    if (ml == 0) {
        const float bmu0 = bmu[0], blv0 = blv[0], beta0 = beta[0];
        #pragma unroll
        for (int r = 0; r < 4; ++r) {
            int n = n0 + 4 * q + r;
            float mu = elu(acc[r] + bmu0);
            float lv = elu(alv4[r] + blv0);
            float z  = mu + eps[b * N_ + n] * expf(0.5f * lv);
            float vs = 1.f / (1.f + expf(-beta0 * z));
            vv[b * N_ + n]   = vs;
            wvbf[b * N_ + n] = f2bf(vs / deg[b * N_ + n]);
            float e = expf(lv);
            klv += 1.f + 2.f * lv - mu * mu - e * e;
        }
    }
    klv += __shfl_xor(klv, 16);
    klv += __shfl_xor(klv, 32);
    if (lane == 0) kls[wave] = klv;
    __syncthreads();
    if (threadIdx.x == 0)
        kl_part[b * 8 + blockIdx.x] = kls[0] + kls[1] + kls[2] + kls[3];
}

// ---------------- k6: p = g@w via MFMA; d = ELU(p*W_dec+b_dec); mse + hp partials ----------------
__global__ __launch_bounds__(256) void k6_dec(const unsigned short* __restrict__ gbf,
                                              const unsigned short* __restrict__ wvbf,
                                              const float* __restrict__ vv,
                                              const unsigned short* __restrict__ h1q,
                                              const float* __restrict__ Wdec, const float* __restrict__ bdec,
                                              float* __restrict__ hp_part, float* __restrict__ mse_part) {
    __shared__ float hps[4 * 64];
    __shared__ float mses[4];
    const int b = blockIdx.y;
    const int tid = threadIdx.x, wave = tid >> 6, lane = tid & 63;
    const int ml = lane & 15, q = lane >> 4;
    const int n0 = (blockIdx.x * 4 + wave) * 16;

    const unsigned short* A  = gbf  + (size_t)(b * N_ + n0 + ml) * N_ + q * 8;
    const unsigned short* Bp = wvbf + (size_t)b * N_ + q * 8;

    f32x4 acc = {};
    #pragma unroll
    for (int k = 0; k < N_; k += 32) {
        bf8_t a  = *reinterpret_cast<const bf8_t*>(A + k);
        bf8_t bb = *reinterpret_cast<const bf8_t*>(Bp + k);
        acc = __builtin_amdgcn_mfma_f32_16x16x32_bf16(a, bb, acc, 0, 0, 0);
    }
    float pbc[16];
    #pragma unroll
    for (int t = 0; t < 16; ++t) pbc[t] = __shfl(acc[t & 3], (t >> 2) << 4);

    const float wd = Wdec[lane], bd = bdec[lane];
    float hpl = 0.f, msep = 0.f;
    #pragma unroll 4
    for (int t = 0; t < 16; ++t) {
        int n = n0 + t;
        float dv  = elu(pbc[t] * wd + bd);
        float h1v = bf2f(h1q[(size_t)(b * N_ + n) * L_ + lane]);
        float diff = h1v - dv;
        msep = fmaf(diff, diff, msep);
        hpl  = fmaf(h1v, vv[b * N_ + n], hpl);
    }
    hps[wave * 64 + lane] = hpl;
    #pragma unroll
    for (int o = 32; o; o >>= 1) msep += __shfl_xor(msep, o);
    if (lane == 0) mses[wave] = msep;
    __syncthreads();
    if (tid < 64) {
        float s = hps[tid] + hps[64 + tid] + hps[128 + tid] + hps[192 + tid];
        hp_part[(size_t)blockIdx.x * (B_ * 64) + b * 64 + tid] = s;
    }
    if (tid == 0)
        mse_part[b * 8 + blockIdx.x] = mses[0] + mses[1] + mses[2] + mses[3];
}

// ---------------- k7: per-batch head + ticketed final reduce (last block) ----------------
__global__ __launch_bounds__(128) void k7_head(const float* __restrict__ hp_part,
                                               const float* __restrict__ W1, const float* __restrict__ b1,
                                               const float* __restrict__ W2, const float* __restrict__ b2,
                                               const int* __restrict__ labels,
                                               const float* __restrict__ kl_part, const float* __restrict__ mse_part,
                                               float* __restrict__ lp, float* __restrict__ cor,
                                               float* __restrict__ klb, float* __restrict__ mseb,
                                               unsigned* __restrict__ ticket, float* __restrict__ out) {
    __shared__ float hps[64];
    __shared__ float acts[128];
    __shared__ float lgs[10];
    __shared__ unsigned sold;
    const int b = blockIdx.x, tid = threadIdx.x;
    if (tid < 64) {
        float s = 0.f;
        #pragma unroll
        for (int x = 0; x < 8; ++x) s += hp_part[(size_t)x * (B_ * 64) + b * 64 + tid];
        hps[tid] = s;
    }
    __syncthreads();
    float s0 = 0, s1 = 0, s2 = 0, s3 = 0;
    for (int l = 0; l < 64; l += 4) {
        s0 += hps[l]     * W1[(l)     * H_ + tid];
        s1 += hps[l + 1] * W1[(l + 1) * H_ + tid];
        s2 += hps[l + 2] * W1[(l + 2) * H_ + tid];
        s3 += hps[l + 3] * W1[(l + 3) * H_ + tid];
    }
    acts[tid] = elu((s0 + s1) + (s2 + s3) + b1[tid]);
    __syncthreads();
    if (tid < C_) {
        float lg = b2[tid];
        for (int hh = 0; hh < H_; ++hh) lg += acts[hh] * W2[hh * C_ + tid];
        lgs[tid] = lg;
    }
    __syncthreads();
    if (tid == 0) {
        float mx = lgs[0]; int am = 0;
        for (int c = 1; c < C_; ++c) if (lgs[c] > mx) { mx = lgs[c]; am = c; }
        float se = 0.f;
        for (int c = 0; c < C_; ++c) se += expf(lgs[c] - mx);
        int lbl = labels[b];
        lp[b]  = lgs[lbl] - mx - logf(se);
        cor[b] = (am == lbl) ? 1.f : 0.f;
    }
    if (tid == 1) {
        float kk = 0.f;
        #pragma unroll
        for (int c = 0; c < 8; ++c) kk += kl_part[b * 8 + c];
        klb[b] = kk;
    }
    if (tid == 2) {
        float mm = 0.f;
        #pragma unroll
        for (int c = 0; c < 8; ++c) mm += mse_part[b * 8 + c];
        mseb[b] = mm;
    }
    if (tid < 3) __threadfence();   // release this block's results device-wide
    __syncthreads();
    if (tid == 0) sold = atomicAdd(ticket, 1u);
    __syncthreads();
    if (sold == 127u) {             // last block: all 128 results visible
        __threadfence();            // acquire
        __shared__ float r1[128], r2[128], r3[128], r4[128];
        r1[tid] = lp[tid]; r2[tid] = cor[tid]; r3[tid] = klb[tid]; r4[tid] = mseb[tid];
        __syncthreads();
        for (int o = 64; o; o >>= 1) {
            if (tid < o) { r1[tid] += r1[tid + o]; r2[tid] += r2[tid + o];
                           r3[tid] += r3[tid + o]; r4[tid] += r4[tid + o]; }
            __syncthreads();
        }
        if (tid == 0) {
            float nll = -r1[0] / (float)B_;
            float kl  = r3[0] * (-0.5f / (65536.f * 65536.f));   // (-0.5/M)*(sum/M), M = B*N
            float mse = r4[0] / (float)(B_ * N_ * L_);
            out[0] = nll + kl + mse;
            out[1] = r2[0] / (float)B_;
        }
    }
}

extern "C" void kernel_launch(void* const* d_in, const int* in_sizes, int n_in,
                              void* d_out, int out_size, void* d_ws, size_t ws_size,
                              hipStream_t stream) {
    const float* g     = (const float*)d_in[0];
    const float* h     = (const float*)d_in[1];
    const int*   labels= (const int*)  d_in[2];
    const float* eps   = (const float*)d_in[3];
    const float* W_s   = (const float*)d_in[4];
    const float* b_s   = (const float*)d_in[5];
    const float* W_mu  = (const float*)d_in[6];
    const float* b_mu  = (const float*)d_in[7];
    const float* W_lv  = (const float*)d_in[8];
    const float* b_lv  = (const float*)d_in[9];
    const float* W_dec = (const float*)d_in[10];
    const float* b_dec = (const float*)d_in[11];
    const float* W1    = (const float*)d_in[12];
    const float* b1    = (const float*)d_in[13];
    const float* W2    = (const float*)d_in[14];
    const float* b2    = (const float*)d_in[15];
    const float* beta  = (const float*)d_in[16];

    float* ws = (float*)d_ws;
    float* deg_part = ws + OFF_DEGP;
    float* deg      = ws + OFF_DEG;
    float* hp_part  = ws + OFF_HPP;
    float* kl_part  = ws + OFF_KLP;
    float* mse_part = ws + OFF_MSEP;
    float* vv       = ws + OFF_V;
    float* lp       = ws + OFF_LP;
    float* cor      = ws + OFF_COR;
    float* klb      = ws + OFF_KLB;
    float* mseb     = ws + OFF_MSEB;
    unsigned* ticket = (unsigned*)(ws + OFF_TICKET);
    unsigned short* tmubf = (unsigned short*)(ws + OFF_TMUBF);
    unsigned short* tlvbf = (unsigned short*)(ws + OFF_TLVBF);
    unsigned short* wvbf  = (unsigned short*)(ws + OFF_WVBF);
    unsigned short* h1q   = (unsigned short*)(ws + OFF_H1Q);
    unsigned short* gbf   = (unsigned short*)(ws + OFF_GBF);
    unsigned short* ubfT  = (unsigned short*)(ws + OFF_UBFT);
    unsigned short* WsTbf = (unsigned short*)(ws + OFF_WSTBF);

    k1_deg <<<dim3(16, B_), 256, 0, stream>>>(g, W_s, deg_part, gbf, WsTbf, ticket);
    k2_u   <<<dim3(8, B_), 256, 0, stream>>>(h, WsTbf, deg_part, deg, ubfT);
    k3_h1  <<<dim3(8, B_), 256, 0, stream>>>(gbf, ubfT, b_s, W_mu, W_lv, deg, h1q, tmubf, tlvbf);
    k5_v   <<<dim3(8, B_), 256, 0, stream>>>(gbf, tmubf, tlvbf, eps, deg, b_mu, b_lv, beta, vv, wvbf, kl_part);
    k6_dec <<<dim3(8, B_), 256, 0, stream>>>(gbf, wvbf, vv, h1q, W_dec, b_dec, hp_part, mse_part);
    k7_head<<<B_, 128, 0, stream>>>(hp_part, W1, b1, W2, b2, labels, kl_part, mse_part,
                                    lp, cor, klb, mseb, ticket, (float*)d_out);
}

// Round 9
// 354.771 us; speedup vs baseline: 1.0260x; 1.0026x over previous
//
#include <hip/hip_runtime.h>

// ---------------- problem constants ----------------
#define B_  128
#define N_  512
#define F_  128
#define L_  64
#define H_  128
#define C_  10

typedef short  bf8_t  __attribute__((ext_vector_type(8)));   // 8 x bf16 (MFMA A/B frag)
typedef float  f32x4  __attribute__((ext_vector_type(4)));   // MFMA C/D frag
typedef unsigned short us8 __attribute__((ext_vector_type(8)));

static __device__ __forceinline__ unsigned short f2bf(float x) {
    union { float f; unsigned u; } c; c.f = x;
    unsigned r = (c.u + 0x7fffu + ((c.u >> 16) & 1u)) >> 16;
    return (unsigned short)r;
}
static __device__ __forceinline__ float bf2f(unsigned short s) {
    union { unsigned u; float f; } c; c.u = ((unsigned)s) << 16;
    return c.f;
}
static __device__ __forceinline__ float elu(float x) { return x > 0.f ? x : expm1f(x); }

// ws layout (float units) — ticket zeroed by k1 each launch; nothing else needs init
#define OFF_DEGP   0           // 4194304  deg partials [b][64][512]
#define OFF_DEG    4194304     // 65536
#define OFF_HPP    4259840     // 65536    hp partials [8][b][64]
#define OFF_KLP    4325376     // 1024     [b*8+c]
#define OFF_MSEP   4326400     // 1024     [b*8+c]
#define OFF_V      4327424     // 65536    v (f32)
#define OFF_LP     4392960     // 128
#define OFF_COR    4393088     // 128
#define OFF_KLB    4393216     // 128      per-batch kl sums
#define OFF_MSEB   4393344     // 128      per-batch mse sums
#define OFF_TMUBF  4393472     // 16384 fl tmu bf16 [b][512]
#define OFF_TLVBF  4409856     // 16384 fl tlv bf16
#define OFF_WVBF   4426240     // 16384 fl w bf16
#define OFF_H1Q    4442624     // 2097152  h1 bf16 [b][n][l]
#define OFF_GBF    6539776     // 16777216 g bf16 [b][n][m]
#define OFF_UBFT   23316992    // 2097152  u^T bf16 [b][l][m]
#define OFF_WSTBF  25414144    // 4096     W_s^T bf16
#define OFF_TICKET 25418240    // 1 uint

// ---------------- k1: g -> bf16 + column-sum partials; 4-row register staging for MLP ----------------
// grid (16,B); block c covers rows [c*32,+32); wave w owns 8 rows; lane owns 8 cols.
// 8 independent dwordx4 loads issued per group before any use -> ~8KB/wave in flight.
__global__ __launch_bounds__(256) void k1_deg(const float* __restrict__ g,
                                              const float* __restrict__ Ws,
                                              float* __restrict__ deg_part,
                                              unsigned short* __restrict__ gbf,
                                              unsigned short* __restrict__ WsTbf,
                                              unsigned* __restrict__ ticket) {
    const int c = blockIdx.x, b = blockIdx.y;
    if (c == 0 && b == 0) {
        if (threadIdx.x == 0) *ticket = 0u;
        for (int i = threadIdx.x; i < F_ * L_; i += 256) {
            int l = i >> 7, f = i & 127;                 // dest [l][f]
            WsTbf[i] = f2bf(Ws[f * L_ + l]);
        }
    }
    const int w = threadIdx.x >> 6, lane = threadIdx.x & 63;
    const int r0 = c * 32 + w * 8;
    const float*    gp = g   + ((size_t)b * N_ + r0) * N_ + lane * 8;
    unsigned short* gq = gbf + ((size_t)b * N_ + r0) * N_ + lane * 8;
    float cs[8] = {};
    #pragma unroll
    for (int g4 = 0; g4 < 2; ++g4) {
        float4 va[8];
        #pragma unroll
        for (int r = 0; r < 4; ++r) {
            const float* p = gp + (size_t)(g4 * 4 + r) * N_;
            va[2 * r]     = *reinterpret_cast<const float4*>(p);
            va[2 * r + 1] = *reinterpret_cast<const float4*>(p + 4);
        }
        #pragma unroll
        for (int r = 0; r < 4; ++r) {
            float4 v0 = va[2 * r], v1 = va[2 * r + 1];
            cs[0] += v0.x; cs[1] += v0.y; cs[2] += v0.z; cs[3] += v0.w;
            cs[4] += v1.x; cs[5] += v1.y; cs[6] += v1.z; cs[7] += v1.w;
            us8 qv;
            qv[0] = f2bf(v0.x); qv[1] = f2bf(v0.y); qv[2] = f2bf(v0.z); qv[3] = f2bf(v0.w);
            qv[4] = f2bf(v1.x); qv[5] = f2bf(v1.y); qv[6] = f2bf(v1.z); qv[7] = f2bf(v1.w);
            *reinterpret_cast<us8*>(gq + (size_t)(g4 * 4 + r) * N_) = qv;
        }
    }
    const int s = c * 4 + w;   // slice 0..63
    float* dp = deg_part + ((size_t)(b * 64 + s)) * N_ + lane * 8;
    *reinterpret_cast<float4*>(dp)     = make_float4(cs[0], cs[1], cs[2], cs[3]);
    *reinterpret_cast<float4*>(dp + 4) = make_float4(cs[4], cs[5], cs[6], cs[7]);
}

// ---------------- k2: finalize deg (64 slices); u^T (bf16) = ((h @ W_s)/deg)^T via MFMA ----------------
__global__ __launch_bounds__(256) void k2_u(const float* __restrict__ h,
                                            const unsigned short* __restrict__ WsTbf,
                                            const float* __restrict__ deg_part,
                                            float* __restrict__ deg,
                                            unsigned short* __restrict__ ubfT) {
    __shared__ float tile[64 * 65];
    __shared__ float sdeg[64];
    const int b    = blockIdx.y;
    const int m0   = blockIdx.x * 64;
    const int tid  = threadIdx.x;
    const int wave = tid >> 6, lane = tid & 63;
    const int ml = lane & 15, q = lane >> 4;
    const int row0 = wave * 16;

    if (tid < 64) {
        int j = m0 + tid;
        float s = 0.f;
        #pragma unroll
        for (int k = 0; k < 64; ++k) s += deg_part[(size_t)(b * 64 + k) * N_ + j];
        sdeg[tid] = s;
        deg[b * N_ + j] = s;
    }

    const float* A = h + (size_t)(b * N_ + m0 + row0 + ml) * F_ + q * 8;
    const unsigned short* Bb = WsTbf + ml * F_ + q * 8;

    f32x4 acc[4] = {};
    #pragma unroll
    for (int kk = 0; kk < F_; kk += 32) {
        float4 a0 = *reinterpret_cast<const float4*>(A + kk);
        float4 a1 = *reinterpret_cast<const float4*>(A + kk + 4);
        union { unsigned short s[8]; bf8_t v; } av;
        av.s[0] = f2bf(a0.x); av.s[1] = f2bf(a0.y); av.s[2] = f2bf(a0.z); av.s[3] = f2bf(a0.w);
        av.s[4] = f2bf(a1.x); av.s[5] = f2bf(a1.y); av.s[6] = f2bf(a1.z); av.s[7] = f2bf(a1.w);
        #pragma unroll
        for (int i = 0; i < 4; ++i) {
            bf8_t bv = *reinterpret_cast<const bf8_t*>(Bb + i * 16 * F_ + kk);
            acc[i] = __builtin_amdgcn_mfma_f32_16x16x32_bf16(av.v, bv, acc[i], 0, 0, 0);
        }
    }
    __syncthreads();   // sdeg ready; tile not yet written
    #pragma unroll
    for (int i = 0; i < 4; ++i) {
        int col = i * 16 + ml;
        #pragma unroll
        for (int r = 0; r < 4; ++r) {
            int rl = row0 + 4 * q + r;
            tile[rl * 65 + col] = acc[i][r] / sdeg[rl];
        }
    }
    __syncthreads();
    for (int jj = 0; jj < 16; ++jj) {
        int ll = wave + jj * 4;
        ubfT[(size_t)(b * L_ + ll) * N_ + m0 + lane] = f2bf(tile[lane * 65 + ll]);
    }
}

// ---------------- k3: h1 = ELU(g@u + b_s) via MFMA; fused tmu/tlv (bf16) ----------------
__global__ __launch_bounds__(256) void k3_h1(const unsigned short* __restrict__ gbf,
                                             const unsigned short* __restrict__ ubfT,
                                             const float* __restrict__ b_s,
                                             const float* __restrict__ Wmu,
                                             const float* __restrict__ Wlv,
                                             const float* __restrict__ deg,
                                             unsigned short* __restrict__ h1q,
                                             unsigned short* __restrict__ tmubf,
                                             unsigned short* __restrict__ tlvbf) {
    const int b    = blockIdx.y;
    const int tid  = threadIdx.x;
    const int wave = tid >> 6, lane = tid & 63;
    const int row0 = blockIdx.x * 64 + wave * 16;
    const int ml = lane & 15, q = lane >> 4;

    const unsigned short* A  = gbf  + (size_t)(b * N_ + row0 + ml) * N_ + q * 8;
    const unsigned short* B0 = ubfT + (size_t)(b * L_ + ml) * N_ + q * 8;

    f32x4 acc[4] = {};
    #pragma unroll 4
    for (int k = 0; k < N_; k += 32) {
        bf8_t a = *reinterpret_cast<const bf8_t*>(A + k);
        #pragma unroll
        for (int i = 0; i < 4; ++i) {
            bf8_t bb = *reinterpret_cast<const bf8_t*>(B0 + (size_t)i * 16 * N_ + k);
            acc[i] = __builtin_amdgcn_mfma_f32_16x16x32_bf16(a, bb, acc[i], 0, 0, 0);
        }
    }
    float bsv[4], wm[4], wl[4];
    #pragma unroll
    for (int i = 0; i < 4; ++i) {
        int col = i * 16 + ml;
        bsv[i] = b_s[col]; wm[i] = Wmu[col]; wl[i] = Wlv[col];
    }
    #pragma unroll
    for (int r = 0; r < 4; ++r) {
        int row = row0 + 4 * q + r;
        float pm = 0.f, pl = 0.f;
        #pragma unroll
        for (int i = 0; i < 4; ++i) {
            float hv = elu(acc[i][r] + bsv[i]);
            h1q[(size_t)(b * N_ + row) * L_ + i * 16 + ml] = f2bf(hv);
            pm = fmaf(hv, wm[i], pm);
            pl = fmaf(hv, wl[i], pl);
        }
        #pragma unroll
        for (int o = 1; o < 16; o <<= 1) { pm += __shfl_xor(pm, o); pl += __shfl_xor(pl, o); }
        if (ml == 0) {
            float idg = 1.f / deg[b * N_ + row];
            tmubf[b * N_ + row] = f2bf(pm * idg);
            tlvbf[b * N_ + row] = f2bf(pl * idg);
        }
    }
}

// ---------------- k5: amu/alv via MFMA (B cols 0/1 = tmu/tlv); z -> v, w; KL partial ----------------
__global__ __launch_bounds__(256) void k5_v(const unsigned short* __restrict__ gbf,
                                            const unsigned short* __restrict__ tmubf,
                                            const unsigned short* __restrict__ tlvbf,
                                            const float* __restrict__ eps, const float* __restrict__ deg,
                                            const float* __restrict__ bmu, const float* __restrict__ blv,
                                            const float* __restrict__ beta,
                                            float* __restrict__ vv, unsigned short* __restrict__ wvbf,
                                            float* __restrict__ kl_part) {
    __shared__ float kls[4];
    const int b = blockIdx.y;
    const int wave = threadIdx.x >> 6, lane = threadIdx.x & 63;
    const int ml = lane & 15, q = lane >> 4;
    const int n0 = (blockIdx.x * 4 + wave) * 16;

    const unsigned short* A  = gbf + (size_t)(b * N_ + n0 + ml) * N_ + q * 8;
    const unsigned short* Bp = ((ml & 1) ? tlvbf : tmubf) + (size_t)b * N_ + q * 8;

    f32x4 acc = {};
    #pragma unroll
    for (int k = 0; k < N_; k += 32) {
        bf8_t a  = *reinterpret_cast<const bf8_t*>(A + k);
        bf8_t bb = *reinterpret_cast<const bf8_t*>(Bp + k);
        acc = __builtin_amdgcn_mfma_f32_16x16x32_bf16(a, bb, acc, 0, 0, 0);
    }
    float alv4[4];
    #pragma unroll
    for (int r = 0; r < 4; ++r) alv4[r] = __shfl_xor(acc[r], 1);

    float klv = 0.f;
    if (ml == 0) {
        const float bmu0 = bmu[0], blv0 = blv[0], beta0 = beta[0];
        #pragma unroll
        for (int r = 0; r < 4; ++r) {
            int n = n0 + 4 * q + r;
            float mu = elu(acc[r] + bmu0);
            float lv = elu(alv4[r] + blv0);
            float z  = mu + eps[b * N_ + n] * expf(0.5f * lv);
            float vs = 1.f / (1.f + expf(-beta0 * z));
            vv[b * N_ + n]   = vs;
            wvbf[b * N_ + n] = f2bf(vs / deg[b * N_ + n]);
            float e = expf(lv);
            klv += 1.f + 2.f * lv - mu * mu - e * e;
        }
    }
    klv += __shfl_xor(klv, 16);
    klv += __shfl_xor(klv, 32);
    if (lane == 0) kls[wave] = klv;
    __syncthreads();
    if (threadIdx.x == 0)
        kl_part[b * 8 + blockIdx.x] = kls[0] + kls[1] + kls[2] + kls[3];
}

// ---------------- k6: p = g@w via MFMA; d = ELU(p*W_dec+b_dec); mse + hp partials ----------------
__global__ __launch_bounds__(256) void k6_dec(const unsigned short* __restrict__ gbf,
                                              const unsigned short* __restrict__ wvbf,
                                              const float* __restrict__ vv,
                                              const unsigned short* __restrict__ h1q,
                                              const float* __restrict__ Wdec, const float* __restrict__ bdec,
                                              float* __restrict__ hp_part, float* __restrict__ mse_part) {
    __shared__ float hps[4 * 64];
    __shared__ float mses[4];
    const int b = blockIdx.y;
    const int tid = threadIdx.x, wave = tid >> 6, lane = tid & 63;
    const int ml = lane & 15, q = lane >> 4;
    const int n0 = (blockIdx.x * 4 + wave) * 16;

    const unsigned short* A  = gbf  + (size_t)(b * N_ + n0 + ml) * N_ + q * 8;
    const unsigned short* Bp = wvbf + (size_t)b * N_ + q * 8;

    f32x4 acc = {};
    #pragma unroll
    for (int k = 0; k < N_; k += 32) {
        bf8_t a  = *reinterpret_cast<const bf8_t*>(A + k);
        bf8_t bb = *reinterpret_cast<const bf8_t*>(Bp + k);
        acc = __builtin_amdgcn_mfma_f32_16x16x32_bf16(a, bb, acc, 0, 0, 0);
    }
    float pbc[16];
    #pragma unroll
    for (int t = 0; t < 16; ++t) pbc[t] = __shfl(acc[t & 3], (t >> 2) << 4);

    const float wd = Wdec[lane], bd = bdec[lane];
    float hpl = 0.f, msep = 0.f;
    #pragma unroll 4
    for (int t = 0; t < 16; ++t) {
        int n = n0 + t;
        float dv  = elu(pbc[t] * wd + bd);
        float h1v = bf2f(h1q[(size_t)(b * N_ + n) * L_ + lane]);
        float diff = h1v - dv;
        msep = fmaf(diff, diff, msep);
        hpl  = fmaf(h1v, vv[b * N_ + n], hpl);
    }
    hps[wave * 64 + lane] = hpl;
    #pragma unroll
    for (int o = 32; o; o >>= 1) msep += __shfl_xor(msep, o);
    if (lane == 0) mses[wave] = msep;
    __syncthreads();
    if (tid < 64) {
        float s = hps[tid] + hps[64 + tid] + hps[128 + tid] + hps[192 + tid];
        hp_part[(size_t)blockIdx.x * (B_ * 64) + b * 64 + tid] = s;
    }
    if (tid == 0)
        mse_part[b * 8 + blockIdx.x] = mses[0] + mses[1] + mses[2] + mses[3];
}

// ---------------- k7: per-batch head + ticketed final reduce (last block) ----------------
__global__ __launch_bounds__(128) void k7_head(const float* __restrict__ hp_part,
                                               const float* __restrict__ W1, const float* __restrict__ b1,
                                               const float* __restrict__ W2, const float* __restrict__ b2,
                                               const int* __restrict__ labels,
                                               const float* __restrict__ kl_part, const float* __restrict__ mse_part,
                                               float* __restrict__ lp, float* __restrict__ cor,
                                               float* __restrict__ klb, float* __restrict__ mseb,
                                               unsigned* __restrict__ ticket, float* __restrict__ out) {
    __shared__ float hps[64];
    __shared__ float acts[128];
    __shared__ float lgs[10];
    __shared__ unsigned sold;
    const int b = blockIdx.x, tid = threadIdx.x;
    if (tid < 64) {
        float s = 0.f;
        #pragma unroll
        for (int x = 0; x < 8; ++x) s += hp_part[(size_t)x * (B_ * 64) + b * 64 + tid];
        hps[tid] = s;
    }
    __syncthreads();
    float s0 = 0, s1 = 0, s2 = 0, s3 = 0;
    for (int l = 0; l < 64; l += 4) {
        s0 += hps[l]     * W1[(l)     * H_ + tid];
        s1 += hps[l + 1] * W1[(l + 1) * H_ + tid];
        s2 += hps[l + 2] * W1[(l + 2) * H_ + tid];
        s3 += hps[l + 3] * W1[(l + 3) * H_ + tid];
    }
    acts[tid] = elu((s0 + s1) + (s2 + s3) + b1[tid]);
    __syncthreads();
    if (tid < C_) {
        float lg = b2[tid];
        for (int hh = 0; hh < H_; ++hh) lg += acts[hh] * W2[hh * C_ + tid];
        lgs[tid] = lg;
    }
    __syncthreads();
    if (tid == 0) {
        float mx = lgs[0]; int am = 0;
        for (int c = 1; c < C_; ++c) if (lgs[c] > mx) { mx = lgs[c]; am = c; }
        float se = 0.f;
        for (int c = 0; c < C_; ++c) se += expf(lgs[c] - mx);
        int lbl = labels[b];
        lp[b]  = lgs[lbl] - mx - logf(se);
        cor[b] = (am == lbl) ? 1.f : 0.f;
    }
    if (tid == 1) {
        float kk = 0.f;
        #pragma unroll
        for (int c = 0; c < 8; ++c) kk += kl_part[b * 8 + c];
        klb[b] = kk;
    }
    if (tid == 2) {
        float mm = 0.f;
        #pragma unroll
        for (int c = 0; c < 8; ++c) mm += mse_part[b * 8 + c];
        mseb[b] = mm;
    }
    if (tid < 3) __threadfence();   // release this block's results device-wide
    __syncthreads();
    if (tid == 0) sold = atomicAdd(ticket, 1u);
    __syncthreads();
    if (sold == 127u) {             // last block: all 128 results visible
        __threadfence();            // acquire
        __shared__ float r1[128], r2[128], r3[128], r4[128];
        r1[tid] = lp[tid]; r2[tid] = cor[tid]; r3[tid] = klb[tid]; r4[tid] = mseb[tid];
        __syncthreads();
        for (int o = 64; o; o >>= 1) {
            if (tid < o) { r1[tid] += r1[tid + o]; r2[tid] += r2[tid + o];
                           r3[tid] += r3[tid + o]; r4[tid] += r4[tid + o]; }
            __syncthreads();
        }
        if (tid == 0) {
            float nll = -r1[0] / (float)B_;
            float kl  = r3[0] * (-0.5f / (65536.f * 65536.f));   // (-0.5/M)*(sum/M), M = B*N
            float mse = r4[0] / (float)(B_ * N_ * L_);
            out[0] = nll + kl + mse;
            out[1] = r2[0] / (float)B_;
        }
    }
}

extern "C" void kernel_launch(void* const* d_in, const int* in_sizes, int n_in,
                              void* d_out, int out_size, void* d_ws, size_t ws_size,
                              hipStream_t stream) {
    const float* g     = (const float*)d_in[0];
    const float* h     = (const float*)d_in[1];
    const int*   labels= (const int*)  d_in[2];
    const float* eps   = (const float*)d_in[3];
    const float* W_s   = (const float*)d_in[4];
    const float* b_s   = (const float*)d_in[5];
    const float* W_mu  = (const float*)d_in[6];
    const float* b_mu  = (const float*)d_in[7];
    const float* W_lv  = (const float*)d_in[8];
    const float* b_lv  = (const float*)d_in[9];
    const float* W_dec = (const float*)d_in[10];
    const float* b_dec = (const float*)d_in[11];
    const float* W1    = (const float*)d_in[12];
    const float* b1    = (const float*)d_in[13];
    const float* W2    = (const float*)d_in[14];
    const float* b2    = (const float*)d_in[15];
    const float* beta  = (const float*)d_in[16];

    float* ws = (float*)d_ws;
    float* deg_part = ws + OFF_DEGP;
    float* deg      = ws + OFF_DEG;
    float* hp_part  = ws + OFF_HPP;
    float* kl_part  = ws + OFF_KLP;
    float* mse_part = ws + OFF_MSEP;
    float* vv       = ws + OFF_V;
    float* lp       = ws + OFF_LP;
    float* cor      = ws + OFF_COR;
    float* klb      = ws + OFF_KLB;
    float* mseb     = ws + OFF_MSEB;
    unsigned* ticket = (unsigned*)(ws + OFF_TICKET);
    unsigned short* tmubf = (unsigned short*)(ws + OFF_TMUBF);
    unsigned short* tlvbf = (unsigned short*)(ws + OFF_TLVBF);
    unsigned short* wvbf  = (unsigned short*)(ws + OFF_WVBF);
    unsigned short* h1q   = (unsigned short*)(ws + OFF_H1Q);
    unsigned short* gbf   = (unsigned short*)(ws + OFF_GBF);
    unsigned short* ubfT  = (unsigned short*)(ws + OFF_UBFT);
    unsigned short* WsTbf = (unsigned short*)(ws + OFF_WSTBF);

    k1_deg <<<dim3(16, B_), 256, 0, stream>>>(g, W_s, deg_part, gbf, WsTbf, ticket);
    k2_u   <<<dim3(8, B_), 256, 0, stream>>>(h, WsTbf, deg_part, deg, ubfT);
    k3_h1  <<<dim3(8, B_), 256, 0, stream>>>(gbf, ubfT, b_s, W_mu, W_lv, deg, h1q, tmubf, tlvbf);
    k5_v   <<<dim3(8, B_), 256, 0, stream>>>(gbf, tmubf, tlvbf, eps, deg, b_mu, b_lv, beta, vv, wvbf, kl_part);
    k6_dec <<<dim3(8, B_), 256, 0, stream>>>(gbf, wvbf, vv, h1q, W_dec, b_dec, hp_part, mse_part);
    k7_head<<<B_, 128, 0, stream>>>(hp_part, W1, b1, W2, b2, labels, kl_part, mse_part,
                                    lp, cor, klb, mseb, ticket, (float*)d_out);
}

// Round 10
// 342.994 us; speedup vs baseline: 1.0612x; 1.0343x over previous
//
#include <hip/hip_runtime.h>

// ---------------- problem constants ----------------
#define B_  128
#define N_  512
#define F_  128
#define L_  64
#define H_  128
#define C_  10

typedef short  bf8_t  __attribute__((ext_vector_type(8)));   // 8 x bf16 (MFMA A/B frag)
typedef float  f32x4  __attribute__((ext_vector_type(4)));   // MFMA C/D frag
typedef unsigned short us8 __attribute__((ext_vector_type(8)));

static __device__ __forceinline__ unsigned short f2bf(float x) {
    union { float f; unsigned u; } c; c.f = x;
    unsigned r = (c.u + 0x7fffu + ((c.u >> 16) & 1u)) >> 16;
    return (unsigned short)r;
}
static __device__ __forceinline__ float bf2f(unsigned short s) {
    union { unsigned u; float f; } c; c.u = ((unsigned)s) << 16;
    return c.f;
}
static __device__ __forceinline__ float elu(float x) { return x > 0.f ? x : expm1f(x); }

// ws layout (float units) — ticket zeroed by k1 each launch; nothing else needs init
#define OFF_DEGP   0           // 4194304  deg partials [b][64][512]
#define OFF_DEG    4194304     // 65536
#define OFF_HPP    4259840     // 65536    hp partials [8][b][64]
#define OFF_KLP    4325376     // 1024     [b*8+c]
#define OFF_MSEP   4326400     // 1024     [b*8+c]
#define OFF_V      4327424     // 65536    v (f32)
#define OFF_LP     4392960     // 128
#define OFF_COR    4393088     // 128
#define OFF_KLB    4393216     // 128      per-batch kl sums
#define OFF_MSEB   4393344     // 128      per-batch mse sums
#define OFF_TMUBF  4393472     // 16384 fl tmu bf16 [b][512]
#define OFF_TLVBF  4409856     // 16384 fl tlv bf16
#define OFF_WVBF   4426240     // 16384 fl w bf16
#define OFF_H1Q    4442624     // 2097152  h1 bf16 [b][n][l]
#define OFF_GBF    6539776     // 16777216 g bf16 [b][n][m]
#define OFF_UBFT   23316992    // 2097152  u^T bf16 [b][l][m]
#define OFF_WSTBF  25414144    // 4096     W_s^T bf16
#define OFF_TICKET 25418240    // 1 uint

typedef __attribute__((address_space(3))) unsigned       lds_u32;
typedef const __attribute__((address_space(1))) unsigned glb_u32;

// ---------------- k1: g -> bf16 + column-sum partials; global_load_lds DMA staging ----------------
// grid (16,B); block c covers rows [c*32,+32); wave w owns 8 rows (16 KB staged via 16 DMAs).
// DMA depth (16 KB/wave in flight, VGPR-free) replaces the compiler-defeated register staging.
__global__ __launch_bounds__(256) void k1_deg(const float* __restrict__ g,
                                              const float* __restrict__ Ws,
                                              float* __restrict__ deg_part,
                                              unsigned short* __restrict__ gbf,
                                              unsigned short* __restrict__ WsTbf,
                                              unsigned* __restrict__ ticket) {
    __shared__ float buf[4][8][512];   // 64 KB: [wave][row][col]
    const int c = blockIdx.x, b = blockIdx.y;
    if (c == 0 && b == 0) {
        if (threadIdx.x == 0) *ticket = 0u;
        for (int i = threadIdx.x; i < F_ * L_; i += 256) {
            int l = i >> 7, f = i & 127;                 // dest [l][f]
            WsTbf[i] = f2bf(Ws[f * L_ + l]);
        }
    }
    const int w = threadIdx.x >> 6, lane = threadIdx.x & 63;
    const int r0 = c * 32 + w * 8;
    const float* gp = g + ((size_t)b * N_ + r0) * N_;

    // issue 16 async DMAs (1 KB each): whole 8-row strip in flight before any wait
    #pragma unroll
    for (int r = 0; r < 8; ++r) {
        #pragma unroll
        for (int seg = 0; seg < 2; ++seg) {
            const float* src = gp + (size_t)r * N_ + seg * 256 + lane * 4;
            __builtin_amdgcn_global_load_lds((glb_u32*)src,
                                             (lds_u32*)&buf[w][r][seg * 256],
                                             16, 0, 0);
        }
    }
    asm volatile("s_waitcnt vmcnt(0)" ::: "memory");

    unsigned short* gq = gbf + ((size_t)b * N_ + r0) * N_ + lane * 8;
    float cs[8] = {};
    #pragma unroll
    for (int r = 0; r < 8; ++r) {
        float4 v0 = *reinterpret_cast<const float4*>(&buf[w][r][lane * 8]);
        float4 v1 = *reinterpret_cast<const float4*>(&buf[w][r][lane * 8 + 4]);
        cs[0] += v0.x; cs[1] += v0.y; cs[2] += v0.z; cs[3] += v0.w;
        cs[4] += v1.x; cs[5] += v1.y; cs[6] += v1.z; cs[7] += v1.w;
        us8 qv;
        qv[0] = f2bf(v0.x); qv[1] = f2bf(v0.y); qv[2] = f2bf(v0.z); qv[3] = f2bf(v0.w);
        qv[4] = f2bf(v1.x); qv[5] = f2bf(v1.y); qv[6] = f2bf(v1.z); qv[7] = f2bf(v1.w);
        *reinterpret_cast<us8*>(gq + (size_t)r * N_) = qv;
    }
    const int s = c * 4 + w;   // slice 0..63
    float* dp = deg_part + ((size_t)(b * 64 + s)) * N_ + lane * 8;
    *reinterpret_cast<float4*>(dp)     = make_float4(cs[0], cs[1], cs[2], cs[3]);
    *reinterpret_cast<float4*>(dp + 4) = make_float4(cs[4], cs[5], cs[6], cs[7]);
}

// ---------------- k2: finalize deg (64 slices); u^T (bf16) = ((h @ W_s)/deg)^T via MFMA ----------------
__global__ __launch_bounds__(256) void k2_u(const float* __restrict__ h,
                                            const unsigned short* __restrict__ WsTbf,
                                            const float* __restrict__ deg_part,
                                            float* __restrict__ deg,
                                            unsigned short* __restrict__ ubfT) {
    __shared__ float tile[64 * 65];
    __shared__ float sdeg[64];
    const int b    = blockIdx.y;
    const int m0   = blockIdx.x * 64;
    const int tid  = threadIdx.x;
    const int wave = tid >> 6, lane = tid & 63;
    const int ml = lane & 15, q = lane >> 4;
    const int row0 = wave * 16;

    if (tid < 64) {
        int j = m0 + tid;
        float s = 0.f;
        #pragma unroll
        for (int k = 0; k < 64; ++k) s += deg_part[(size_t)(b * 64 + k) * N_ + j];
        sdeg[tid] = s;
        deg[b * N_ + j] = s;
    }

    const float* A = h + (size_t)(b * N_ + m0 + row0 + ml) * F_ + q * 8;
    const unsigned short* Bb = WsTbf + ml * F_ + q * 8;

    f32x4 acc[4] = {};
    #pragma unroll
    for (int kk = 0; kk < F_; kk += 32) {
        float4 a0 = *reinterpret_cast<const float4*>(A + kk);
        float4 a1 = *reinterpret_cast<const float4*>(A + kk + 4);
        union { unsigned short s[8]; bf8_t v; } av;
        av.s[0] = f2bf(a0.x); av.s[1] = f2bf(a0.y); av.s[2] = f2bf(a0.z); av.s[3] = f2bf(a0.w);
        av.s[4] = f2bf(a1.x); av.s[5] = f2bf(a1.y); av.s[6] = f2bf(a1.z); av.s[7] = f2bf(a1.w);
        #pragma unroll
        for (int i = 0; i < 4; ++i) {
            bf8_t bv = *reinterpret_cast<const bf8_t*>(Bb + i * 16 * F_ + kk);
            acc[i] = __builtin_amdgcn_mfma_f32_16x16x32_bf16(av.v, bv, acc[i], 0, 0, 0);
        }
    }
    __syncthreads();   // sdeg ready; tile not yet written
    #pragma unroll
    for (int i = 0; i < 4; ++i) {
        int col = i * 16 + ml;
        #pragma unroll
        for (int r = 0; r < 4; ++r) {
            int rl = row0 + 4 * q + r;
            tile[rl * 65 + col] = acc[i][r] / sdeg[rl];
        }
    }
    __syncthreads();
    for (int jj = 0; jj < 16; ++jj) {
        int ll = wave + jj * 4;
        ubfT[(size_t)(b * L_ + ll) * N_ + m0 + lane] = f2bf(tile[lane * 65 + ll]);
    }
}

// ---------------- k3: h1 = ELU(g@u + b_s) via MFMA; fused tmu/tlv (bf16) ----------------
__global__ __launch_bounds__(256) void k3_h1(const unsigned short* __restrict__ gbf,
                                             const unsigned short* __restrict__ ubfT,
                                             const float* __restrict__ b_s,
                                             const float* __restrict__ Wmu,
                                             const float* __restrict__ Wlv,
                                             const float* __restrict__ deg,
                                             unsigned short* __restrict__ h1q,
                                             unsigned short* __restrict__ tmubf,
                                             unsigned short* __restrict__ tlvbf) {
    const int b    = blockIdx.y;
    const int tid  = threadIdx.x;
    const int wave = tid >> 6, lane = tid & 63;
    const int row0 = blockIdx.x * 64 + wave * 16;
    const int ml = lane & 15, q = lane >> 4;

    const unsigned short* A  = gbf  + (size_t)(b * N_ + row0 + ml) * N_ + q * 8;
    const unsigned short* B0 = ubfT + (size_t)(b * L_ + ml) * N_ + q * 8;

    f32x4 acc[4] = {};
    #pragma unroll 4
    for (int k = 0; k < N_; k += 32) {
        bf8_t a = *reinterpret_cast<const bf8_t*>(A + k);
        #pragma unroll
        for (int i = 0; i < 4; ++i) {
            bf8_t bb = *reinterpret_cast<const bf8_t*>(B0 + (size_t)i * 16 * N_ + k);
            acc[i] = __builtin_amdgcn_mfma_f32_16x16x32_bf16(a, bb, acc[i], 0, 0, 0);
        }
    }
    float bsv[4], wm[4], wl[4];
    #pragma unroll
    for (int i = 0; i < 4; ++i) {
        int col = i * 16 + ml;
        bsv[i] = b_s[col]; wm[i] = Wmu[col]; wl[i] = Wlv[col];
    }
    #pragma unroll
    for (int r = 0; r < 4; ++r) {
        int row = row0 + 4 * q + r;
        float pm = 0.f, pl = 0.f;
        #pragma unroll
        for (int i = 0; i < 4; ++i) {
            float hv = elu(acc[i][r] + bsv[i]);
            h1q[(size_t)(b * N_ + row) * L_ + i * 16 + ml] = f2bf(hv);
            pm = fmaf(hv, wm[i], pm);
            pl = fmaf(hv, wl[i], pl);
        }
        #pragma unroll
        for (int o = 1; o < 16; o <<= 1) { pm += __shfl_xor(pm, o); pl += __shfl_xor(pl, o); }
        if (ml == 0) {
            float idg = 1.f / deg[b * N_ + row];
            tmubf[b * N_ + row] = f2bf(pm * idg);
            tlvbf[b * N_ + row] = f2bf(pl * idg);
        }
    }
}

// ---------------- k5: amu/alv via MFMA (B cols 0/1 = tmu/tlv); z -> v, w; KL partial ----------------
__global__ __launch_bounds__(256) void k5_v(const unsigned short* __restrict__ gbf,
                                            const unsigned short* __restrict__ tmubf,
                                            const unsigned short* __restrict__ tlvbf,
                                            const float* __restrict__ eps, const float* __restrict__ deg,
                                            const float* __restrict__ bmu, const float* __restrict__ blv,
                                            const float* __restrict__ beta,
                                            float* __restrict__ vv, unsigned short* __restrict__ wvbf,
                                            float* __restrict__ kl_part) {
    __shared__ float kls[4];
    const int b = blockIdx.y;
    const int wave = threadIdx.x >> 6, lane = threadIdx.x & 63;
    const int ml = lane & 15, q = lane >> 4;
    const int n0 = (blockIdx.x * 4 + wave) * 16;

    const unsigned short* A  = gbf + (size_t)(b * N_ + n0 + ml) * N_ + q * 8;
    const unsigned short* Bp = ((ml & 1) ? tlvbf : tmubf) + (size_t)b * N_ + q * 8;

    f32x4 acc = {};
    #pragma unroll
    for (int k = 0; k < N_; k += 32) {
        bf8_t a  = *reinterpret_cast<const bf8_t*>(A + k);
        bf8_t bb = *reinterpret_cast<const bf8_t*>(Bp + k);
        acc = __builtin_amdgcn_mfma_f32_16x16x32_bf16(a, bb, acc, 0, 0, 0);
    }
    float alv4[4];
    #pragma unroll
    for (int r = 0; r < 4; ++r) alv4[r] = __shfl_xor(acc[r], 1);

    float klv = 0.f;
    if (ml == 0) {
        const float bmu0 = bmu[0], blv0 = blv[0], beta0 = beta[0];
        #pragma unroll
        for (int r = 0; r < 4; ++r) {
            int n = n0 + 4 * q + r;
            float mu = elu(acc[r] + bmu0);
            float lv = elu(alv4[r] + blv0);
            float z  = mu + eps[b * N_ + n] * expf(0.5f * lv);
            float vs = 1.f / (1.f + expf(-beta0 * z));
            vv[b * N_ + n]   = vs;
            wvbf[b * N_ + n] = f2bf(vs / deg[b * N_ + n]);
            float e = expf(lv);
            klv += 1.f + 2.f * lv - mu * mu - e * e;
        }
    }
    klv += __shfl_xor(klv, 16);
    klv += __shfl_xor(klv, 32);
    if (lane == 0) kls[wave] = klv;
    __syncthreads();
    if (threadIdx.x == 0)
        kl_part[b * 8 + blockIdx.x] = kls[0] + kls[1] + kls[2] + kls[3];
}

// ---------------- k6: p = g@w via MFMA; d = ELU(p*W_dec+b_dec); mse + hp partials ----------------
__global__ __launch_bounds__(256) void k6_dec(const unsigned short* __restrict__ gbf,
                                              const unsigned short* __restrict__ wvbf,
                                              const float* __restrict__ vv,
                                              const unsigned short* __restrict__ h1q,
                                              const float* __restrict__ Wdec, const float* __restrict__ bdec,
                                              float* __restrict__ hp_part, float* __restrict__ mse_part) {
    __shared__ float hps[4 * 64];
    __shared__ float mses[4];
    const int b = blockIdx.y;
    const int tid = threadIdx.x, wave = tid >> 6, lane = tid & 63;
    const int ml = lane & 15, q = lane >> 4;
    const int n0 = (blockIdx.x * 4 + wave) * 16;

    const unsigned short* A  = gbf  + (size_t)(b * N_ + n0 + ml) * N_ + q * 8;
    const unsigned short* Bp = wvbf + (size_t)b * N_ + q * 8;

    f32x4 acc = {};
    #pragma unroll
    for (int k = 0; k < N_; k += 32) {
        bf8_t a  = *reinterpret_cast<const bf8_t*>(A + k);
        bf8_t bb = *reinterpret_cast<const bf8_t*>(Bp + k);
        acc = __builtin_amdgcn_mfma_f32_16x16x32_bf16(a, bb, acc, 0, 0, 0);
    }
    float pbc[16];
    #pragma unroll
    for (int t = 0; t < 16; ++t) pbc[t] = __shfl(acc[t & 3], (t >> 2) << 4);

    const float wd = Wdec[lane], bd = bdec[lane];
    float hpl = 0.f, msep = 0.f;
    #pragma unroll 4
    for (int t = 0; t < 16; ++t) {
        int n = n0 + t;
        float dv  = elu(pbc[t] * wd + bd);
        float h1v = bf2f(h1q[(size_t)(b * N_ + n) * L_ + lane]);
        float diff = h1v - dv;
        msep = fmaf(diff, diff, msep);
        hpl  = fmaf(h1v, vv[b * N_ + n], hpl);
    }
    hps[wave * 64 + lane] = hpl;
    #pragma unroll
    for (int o = 32; o; o >>= 1) msep += __shfl_xor(msep, o);
    if (lane == 0) mses[wave] = msep;
    __syncthreads();
    if (tid < 64) {
        float s = hps[tid] + hps[64 + tid] + hps[128 + tid] + hps[192 + tid];
        hp_part[(size_t)blockIdx.x * (B_ * 64) + b * 64 + tid] = s;
    }
    if (tid == 0)
        mse_part[b * 8 + blockIdx.x] = mses[0] + mses[1] + mses[2] + mses[3];
}

// ---------------- k7: per-batch head + ticketed final reduce (last block) ----------------
__global__ __launch_bounds__(128) void k7_head(const float* __restrict__ hp_part,
                                               const float* __restrict__ W1, const float* __restrict__ b1,
                                               const float* __restrict__ W2, const float* __restrict__ b2,
                                               const int* __restrict__ labels,
                                               const float* __restrict__ kl_part, const float* __restrict__ mse_part,
                                               float* __restrict__ lp, float* __restrict__ cor,
                                               float* __restrict__ klb, float* __restrict__ mseb,
                                               unsigned* __restrict__ ticket, float* __restrict__ out) {
    __shared__ float hps[64];
    __shared__ float acts[128];
    __shared__ float lgs[10];
    __shared__ unsigned sold;
    const int b = blockIdx.x, tid = threadIdx.x;
    if (tid < 64) {
        float s = 0.f;
        #pragma unroll
        for (int x = 0; x < 8; ++x) s += hp_part[(size_t)x * (B_ * 64) + b * 64 + tid];
        hps[tid] = s;
    }
    __syncthreads();
    float s0 = 0, s1 = 0, s2 = 0, s3 = 0;
    for (int l = 0; l < 64; l += 4) {
        s0 += hps[l]     * W1[(l)     * H_ + tid];
        s1 += hps[l + 1] * W1[(l + 1) * H_ + tid];
        s2 += hps[l + 2] * W1[(l + 2) * H_ + tid];
        s3 += hps[l + 3] * W1[(l + 3) * H_ + tid];
    }
    acts[tid] = elu((s0 + s1) + (s2 + s3) + b1[tid]);
    __syncthreads();
    if (tid < C_) {
        float lg = b2[tid];
        for (int hh = 0; hh < H_; ++hh) lg += acts[hh] * W2[hh * C_ + tid];
        lgs[tid] = lg;
    }
    __syncthreads();
    if (tid == 0) {
        float mx = lgs[0]; int am = 0;
        for (int c = 1; c < C_; ++c) if (lgs[c] > mx) { mx = lgs[c]; am = c; }
        float se = 0.f;
        for (int c = 0; c < C_; ++c) se += expf(lgs[c] - mx);
        int lbl = labels[b];
        lp[b]  = lgs[lbl] - mx - logf(se);
        cor[b] = (am == lbl) ? 1.f : 0.f;
    }
    if (tid == 1) {
        float kk = 0.f;
        #pragma unroll
        for (int c = 0; c < 8; ++c) kk += kl_part[b * 8 + c];
        klb[b] = kk;
    }
    if (tid == 2) {
        float mm = 0.f;
        #pragma unroll
        for (int c = 0; c < 8; ++c) mm += mse_part[b * 8 + c];
        mseb[b] = mm;
    }
    if (tid < 3) __threadfence();   // release this block's results device-wide
    __syncthreads();
    if (tid == 0) sold = atomicAdd(ticket, 1u);
    __syncthreads();
    if (sold == 127u) {             // last block: all 128 results visible
        __threadfence();            // acquire
        __shared__ float r1[128], r2[128], r3[128], r4[128];
        r1[tid] = lp[tid]; r2[tid] = cor[tid]; r3[tid] = klb[tid]; r4[tid] = mseb[tid];
        __syncthreads();
        for (int o = 64; o; o >>= 1) {
            if (tid < o) { r1[tid] += r1[tid + o]; r2[tid] += r2[tid + o];
                           r3[tid] += r3[tid + o]; r4[tid] += r4[tid + o]; }
            __syncthreads();
        }
        if (tid == 0) {
            float nll = -r1[0] / (float)B_;
            float kl  = r3[0] * (-0.5f / (65536.f * 65536.f));   // (-0.5/M)*(sum/M), M = B*N
            float mse = r4[0] / (float)(B_ * N_ * L_);
            out[0] = nll + kl + mse;
            out[1] = r2[0] / (float)B_;
        }
    }
}

extern "C" void kernel_launch(void* const* d_in, const int* in_sizes, int n_in,
                              void* d_out, int out_size, void* d_ws, size_t ws_size,
                              hipStream_t stream) {
    const float* g     = (const float*)d_in[0];
    const float* h     = (const float*)d_in[1];
    const int*   labels= (const int*)  d_in[2];
    const float* eps   = (const float*)d_in[3];
    const float* W_s   = (const float*)d_in[4];
    const float* b_s   = (const float*)d_in[5];
    const float* W_mu  = (const float*)d_in[6];
    const float* b_mu  = (const float*)d_in[7];
    const float* W_lv  = (const float*)d_in[8];
    const float* b_lv  = (const float*)d_in[9];
    const float* W_dec = (const float*)d_in[10];
    const float* b_dec = (const float*)d_in[11];
    const float* W1    = (const float*)d_in[12];
    const float* b1    = (const float*)d_in[13];
    const float* W2    = (const float*)d_in[14];
    const float* b2    = (const float*)d_in[15];
    const float* beta  = (const float*)d_in[16];

    float* ws = (float*)d_ws;
    float* deg_part = ws + OFF_DEGP;
    float* deg      = ws + OFF_DEG;
    float* hp_part  = ws + OFF_HPP;
    float* kl_part  = ws + OFF_KLP;
    float* mse_part = ws + OFF_MSEP;
    float* vv       = ws + OFF_V;
    float* lp       = ws + OFF_LP;
    float* cor      = ws + OFF_COR;
    float* klb      = ws + OFF_KLB;
    float* mseb     = ws + OFF_MSEB;
    unsigned* ticket = (unsigned*)(ws + OFF_TICKET);
    unsigned short* tmubf = (unsigned short*)(ws + OFF_TMUBF);
    unsigned short* tlvbf = (unsigned short*)(ws + OFF_TLVBF);
    unsigned short* wvbf  = (unsigned short*)(ws + OFF_WVBF);
    unsigned short* h1q   = (unsigned short*)(ws + OFF_H1Q);
    unsigned short* gbf   = (unsigned short*)(ws + OFF_GBF);
    unsigned short* ubfT  = (unsigned short*)(ws + OFF_UBFT);
    unsigned short* WsTbf = (unsigned short*)(ws + OFF_WSTBF);

    k1_deg <<<dim3(16, B_), 256, 0, stream>>>(g, W_s, deg_part, gbf, WsTbf, ticket);
    k2_u   <<<dim3(8, B_), 256, 0, stream>>>(h, WsTbf, deg_part, deg, ubfT);
    k3_h1  <<<dim3(8, B_), 256, 0, stream>>>(gbf, ubfT, b_s, W_mu, W_lv, deg, h1q, tmubf, tlvbf);
    k5_v   <<<dim3(8, B_), 256, 0, stream>>>(gbf, tmubf, tlvbf, eps, deg, b_mu, b_lv, beta, vv, wvbf, kl_part);
    k6_dec <<<dim3(8, B_), 256, 0, stream>>>(gbf, wvbf, vv, h1q, W_dec, b_dec, hp_part, mse_part);
    k7_head<<<B_, 128, 0, stream>>>(hp_part, W1, b1, W2, b2, labels, kl_part, mse_part,
                                    lp, cor, klb, mseb, ticket, (float*)d_out);
}